// Round 8
// baseline (509.681 us; speedup 1.0000x reference)
//
#include <hip/hip_runtime.h>
#include <hip/hip_bf16.h>
#include <cstdint>
#include <cmath>

typedef __attribute__((ext_vector_type(4))) float f32x4;
typedef __attribute__((ext_vector_type(8))) short bf16x8;

#define BAR()   __builtin_amdgcn_s_barrier()
#define PRIO1() __builtin_amdgcn_s_setprio(1)
#define PRIO0() __builtin_amdgcn_s_setprio(0)
#define WAITV8() asm volatile("s_waitcnt vmcnt(8)" ::: "memory")
#define WAITV4() asm volatile("s_waitcnt vmcnt(4)" ::: "memory")
#define WAITV3() asm volatile("s_waitcnt vmcnt(3)" ::: "memory")
#define WAITV0() asm volatile("s_waitcnt vmcnt(0)" ::: "memory")
#define MM(a,b,c) __builtin_amdgcn_mfma_f32_16x16x32_bf16((a),(b),(c),0,0,0)

__device__ __forceinline__ void gl_lds16(const __hip_bfloat16* g, char* l) {
    __builtin_amdgcn_global_load_lds(
        (const __attribute__((address_space(1))) void*)g,
        (__attribute__((address_space(3))) void*)l, 16, 0, 0);
}
__device__ __forceinline__ void store_c(float* C, size_t i, float v) { C[i] = v; }
__device__ __forceinline__ void store_c(__hip_bfloat16* C, size_t i, float v) { C[i] = __float2bfloat16(v); }

// ---------------------------------------------------------------------------
// gemm256: 256x256 tile, BK=32, 8 waves (2Mx4N), FOUR-buffer 128KB LDS,
// 3-TILE-DEEP prefetch: stage(t+3) at tile t; boundary wait = vmcnt(8)
// (keeps t+2/t+3's 8 loads in flight, drains t+1 — issued at t-2, so
// ~2.5 tiles (>800 cyc) of latency cover vs HBM ~900 cyc). Epilogue ladder
// vmcnt 8 -> 4 -> 0. Race-safe sync (R7): BAR / stage / counted-wait / BAR,
// then afH reads + MFMA cluster 1 + read-ahead afL(t+1) + cluster 2 +
// read-ahead bfr(t+1). Write-after-read on buf[(t+3)&3]=(t-1)&3 is protected
// by the top BAR (its last reads happened during tile t-1).
// ---------------------------------------------------------------------------
#define STAGEA(nb, kt) do{ gl_lds16(Asrc + (kt),                        lds + (nb)         + wb); \
                           gl_lds16(Asrc + (size_t)128 * lda + (kt),    lds + (nb) +  8192 + wb);}while(0)
#define STAGEB(nb, kt) do{ gl_lds16(Bsrc + (kt),                        lds + (nb) + 16384 + wb); \
                           gl_lds16(Bsrc + (size_t)128 * ldb + (kt),    lds + (nb) + 24576 + wb);}while(0)

template<typename CT>
__global__ __launch_bounds__(512, 2)
void gemm256(const __hip_bfloat16* __restrict__ A, const __hip_bfloat16* __restrict__ B,
             CT* __restrict__ C, int K, int lda, int ldb, int ldc, int nbx, float alpha)
{
    __shared__ __align__(1024) char lds[131072];

    // bijective XCD-aware swizzle (m204)
    const int nwg = gridDim.x;
    const int q8 = nwg >> 3, r8 = nwg & 7;
    const int xcd = blockIdx.x & 7, blk = blockIdx.x >> 3;
    const int wg = (xcd < r8 ? xcd * (q8 + 1) : r8 * (q8 + 1) + (xcd - r8) * q8) + blk;
    const int bm0 = (wg / nbx) * 256, bn0 = (wg % nbx) * 256;

    const int tid  = threadIdx.x;
    const int lane = tid & 63;
    const int w    = tid >> 6;
    const int wb   = w * 1024;

    const int rb   = (lane & 15) * 64 + (lane >> 4) * 16;
    const int rswz = rb ^ (((rb >> 9) & 1) << 5);
    const int srA  = (w >> 2) * 8;
    const int srB  = (w & 3) * 4;

    const int q0 = tid * 16;
    const int uq = q0 ^ (((q0 >> 9) & 1) << 5);
    const int r0 = ((q0 >> 10) << 4) | ((uq >> 6) & 15);
    const int c0 = (uq & 63) >> 1;
    const __hip_bfloat16* Asrc = A + (size_t)(bm0 + r0) * lda + c0;
    const __hip_bfloat16* Bsrc = B + (size_t)(bn0 + r0) * ldb + c0;

    f32x4 acc[8][4] = {};
    bf16x8 afL[4], afH[4], bfr[4];

    const int nt = K >> 5;                 // = 64 for all our shapes (>=3)

    STAGEA(0, 0);          STAGEB(0, 0);
    STAGEA(32768, 32);     STAGEB(32768, 32);
    STAGEA(65536, 64);     STAGEB(65536, 64);
    WAITV8();                              // own tile-0 loads done
    BAR();                                 // ALL waves' tile-0 loads visible
    {
        const char* dA = lds; const char* dB = lds + 16384;
#pragma unroll
        for (int i = 0; i < 4; ++i) afL[i] = *(const bf16x8*)(dA + ((srA + i) << 10) + rswz);
#pragma unroll
        for (int i = 0; i < 4; ++i) bfr[i] = *(const bf16x8*)(dB + ((srB + i) << 10) + rswz);
    }

    for (int t = 0; t < nt; ++t) {
        BAR();                             // old readers of buf[(t+3)&3] done
        const bool pf3 = (t + 3) < nt;
        if (pf3) { const int nbo = ((t + 3) & 3) * 32768, kt = (t + 3) << 5;
                   STAGEA(nbo, kt); STAGEB(nbo, kt); }
        if (pf3) WAITV8();                 // drain t+1 (issued at t-2), keep t+2,t+3
        else if (t + 2 < nt) WAITV4();     // drain t+1, keep t+2
        else WAITV0();
        BAR();                             // t+1 staging visible to all waves

        const char* dA = lds + (t & 3) * 32768;
#pragma unroll
        for (int i = 0; i < 4; ++i) afH[i] = *(const bf16x8*)(dA + ((srA + 4 + i) << 10) + rswz);

        PRIO1();
#pragma unroll
        for (int mi = 0; mi < 4; ++mi)
#pragma unroll
            for (int ni = 0; ni < 4; ++ni)
                acc[mi][ni] = MM(afL[mi], bfr[ni], acc[mi][ni]);
        PRIO0();

        const bool rd = (t + 1) < nt;
        const char* eA = lds + ((t + 1) & 3) * 32768;
        if (rd) {
#pragma unroll
            for (int i = 0; i < 4; ++i) afL[i] = *(const bf16x8*)(eA + ((srA + i) << 10) + rswz);
        }

        PRIO1();
#pragma unroll
        for (int mi = 0; mi < 4; ++mi)
#pragma unroll
            for (int ni = 0; ni < 4; ++ni)
                acc[4 + mi][ni] = MM(afH[mi], bfr[ni], acc[4 + mi][ni]);
        PRIO0();

        if (rd) {
            const char* eB = eA + 16384;
#pragma unroll
            for (int i = 0; i < 4; ++i) bfr[i] = *(const bf16x8*)(eB + ((srB + i) << 10) + rswz);
        }
    }

    const int cr = (lane >> 4) * 4, cc = lane & 15;
    const int wrow = bm0 + (w >> 2) * 128, wcol = bn0 + (w & 3) * 64;
#pragma unroll
    for (int mi = 0; mi < 8; ++mi)
#pragma unroll
        for (int ni = 0; ni < 4; ++ni) {
            const int row = wrow + mi * 16 + cr;
            const int col = wcol + ni * 16 + cc;
#pragma unroll
            for (int j = 0; j < 4; ++j)
                store_c(C, (size_t)(row + j) * ldc + col, acc[mi][ni][j] * alpha);
        }
}

// ---------------------------------------------------------------------------
// gemm128 (UNCHANGED control): 128x256 tile, BK=32, 3-buffer 72KB LDS,
// 2 blocks/CU, race-safe continuous-issue schedule.
// MODE 1: causal S triangular 128-row blocks. MODE 2: PV, kend=bm0+128.
// ---------------------------------------------------------------------------
#define STG128(buf, kt) do{ \
    gl_lds16(Asrc + (kt),  lds + (buf) * 24576 +         w * 1024); \
    gl_lds16(Bsrc0 + (kt), lds + (buf) * 24576 +  8192 + w * 1024); \
    gl_lds16(Bsrc1 + (kt), lds + (buf) * 24576 + 16384 + w * 1024); }while(0)

template<typename CT, int MODE>
__global__ __launch_bounds__(512, 4)
void gemm128(const __hip_bfloat16* __restrict__ A, const __hip_bfloat16* __restrict__ B,
             CT* __restrict__ C, int K, int lda, int ldb, int ldc, int nbx,
             float alpha, size_t sA, size_t sB, size_t sC)
{
    __shared__ __align__(1024) char lds[73728];

    int bm0, bn0;
    if (MODE == 1) {
        int g = blockIdx.x, r = 0;
        while (g >= (r >> 1) + 1) { g -= (r >> 1) + 1; ++r; }   // <=16 iters
        bm0 = r << 7; bn0 = g << 8;
    } else {
        const int g = blockIdx.x;
        const int nby = gridDim.x / nbx;
        const int bx = g % nbx;
        const int by = (g / nbx + bx) % nby;
        bm0 = by << 7; bn0 = bx << 8;
    }

    A += sA * blockIdx.y; B += sB * blockIdx.y; C += sC * blockIdx.y;

    const int tid  = threadIdx.x;
    const int lane = tid & 63;
    const int w    = tid >> 6;

    const int rb   = (lane & 15) * 64 + (lane >> 4) * 16;
    const int rswz = rb ^ (((rb >> 9) & 1) << 5);
    const int stA  = (w >> 2) * 4;
    const int stB  = (w & 3) * 4;

    const int qA  = tid * 16;
    const int uqA = qA ^ (((qA >> 9) & 1) << 5);
    const int rA  = ((qA >> 10) << 4) | ((uqA >> 6) & 15);
    const int cA  = (uqA & 63) >> 1;
    const int qB1  = 8192 + tid * 16;
    const int uqB1 = qB1 ^ (((qB1 >> 9) & 1) << 5);
    const int rB1  = ((qB1 >> 10) << 4) | ((uqB1 >> 6) & 15);
    const int cB1  = (uqB1 & 63) >> 1;
    const __hip_bfloat16* Asrc  = A + (size_t)(bm0 + rA) * lda + cA;
    const __hip_bfloat16* Bsrc0 = B + (size_t)(bn0 + rA) * ldb + cA;
    const __hip_bfloat16* Bsrc1 = B + (size_t)(bn0 + rB1) * ldb + cB1;

    f32x4 acc[4][4] = {};
    bf16x8 af[4], bfr[4];

    const int klim = bm0 + 128;
    const int kend = (MODE == 2) ? (K < klim ? K : klim) : K;
    const int nt   = kend >> 5;            // >= 4 for all our shapes

    STG128(0, 0); STG128(1, 32);
    WAITV3();                              // own tile-0 loads done
    BAR();                                 // all waves' tile-0 visible
    {
        const char* dA = lds; const char* dB = lds + 8192;
#pragma unroll
        for (int i = 0; i < 4; ++i) af[i]  = *(const bf16x8*)(dA + ((stA + i) << 10) + rswz);
#pragma unroll
        for (int i = 0; i < 4; ++i) bfr[i] = *(const bf16x8*)(dB + ((stB + i) << 10) + rswz);
    }

    for (int t = 0; t < nt; ++t) {
        BAR();                             // old readers of buf[(t+2)%3] done
        const bool pf = (t + 2) < nt;
        if (pf) STG128((t + 2) % 3, (t + 2) << 5);
        if (pf) WAITV3(); else WAITV0();   // drain t+1, keep t+2 in flight
        BAR();                             // t+1 staging visible to all waves

        PRIO1();
#pragma unroll
        for (int mi = 0; mi < 4; ++mi) {
            acc[mi][0] = MM(af[mi], bfr[0], acc[mi][0]);
            acc[mi][1] = MM(af[mi], bfr[1], acc[mi][1]);
        }
        PRIO0();

        const bool rd = (t + 1) < nt;
        const char* eD = lds + ((t + 1) % 3) * 24576;
        if (rd) {
            bfr[0] = *(const bf16x8*)(eD + 8192 + ((stB + 0) << 10) + rswz);
            bfr[1] = *(const bf16x8*)(eD + 8192 + ((stB + 1) << 10) + rswz);
        }

        PRIO1();
#pragma unroll
        for (int mi = 0; mi < 4; ++mi) {
            acc[mi][2] = MM(af[mi], bfr[2], acc[mi][2]);
            acc[mi][3] = MM(af[mi], bfr[3], acc[mi][3]);
        }
        PRIO0();

        if (rd) {
#pragma unroll
            for (int i = 0; i < 4; ++i) af[i] = *(const bf16x8*)(eD + ((stA + i) << 10) + rswz);
            bfr[2] = *(const bf16x8*)(eD + 8192 + ((stB + 2) << 10) + rswz);
            bfr[3] = *(const bf16x8*)(eD + 8192 + ((stB + 3) << 10) + rswz);
        }
    }

    const int cr = (lane >> 4) * 4, cc = lane & 15;
    const int wrow = bm0 + (w >> 2) * 64, wcol = bn0 + (w & 3) * 64;
#pragma unroll
    for (int mi = 0; mi < 4; ++mi)
#pragma unroll
        for (int ni = 0; ni < 4; ++ni) {
            const int row = wrow + mi * 16 + cr;
            const int col = wcol + ni * 16 + cc;
#pragma unroll
            for (int j = 0; j < 4; ++j)
                store_c(C, (size_t)(row + j) * ldc + col, acc[mi][ni][j] * alpha);
        }
}

// ---------------------------------------------------------------------------
__global__ void f32_to_bf16_vec(const float* __restrict__ in,
                                __hip_bfloat16* __restrict__ out, int n4)
{
    int i = blockIdx.x * 256 + threadIdx.x;
    if (i >= n4) return;
    float4 v = ((const float4*)in)[i];
    union { ushort4 u; __hip_bfloat16 h[4]; } o;
    o.h[0] = __float2bfloat16(v.x);
    o.h[1] = __float2bfloat16(v.y);
    o.h[2] = __float2bfloat16(v.z);
    o.h[3] = __float2bfloat16(v.w);
    ((ushort4*)out)[i] = o.u;
}

// 4 weight matrices -> wqkv concat (rows: wq|wk|wv) + wob
__global__ void conv_w4(const float* __restrict__ w0, const float* __restrict__ w1,
                        const float* __restrict__ w2, const float* __restrict__ w3,
                        __hip_bfloat16* o0, __hip_bfloat16* o1,
                        __hip_bfloat16* o2, __hip_bfloat16* o3, int n4)
{
    int i = blockIdx.x * 256 + threadIdx.x;
    if (i >= n4) return;
    const float* src; __hip_bfloat16* dst;
    switch (blockIdx.y) {
        case 0: src = w0; dst = o0; break;
        case 1: src = w1; dst = o1; break;
        case 2: src = w2; dst = o2; break;
        default: src = w3; dst = o3; break;
    }
    float4 v = ((const float4*)src)[i];
    union { ushort4 u; __hip_bfloat16 h[4]; } o;
    o.h[0] = __float2bfloat16(v.x);
    o.h[1] = __float2bfloat16(v.y);
    o.h[2] = __float2bfloat16(v.z);
    o.h[3] = __float2bfloat16(v.w);
    ((ushort4*)dst)[i] = o.u;
}

__global__ void rope_table(const int* __restrict__ pos, float2* __restrict__ tab, int N)
{
    int i = blockIdx.x * 256 + threadIdx.x;
    if (i >= N * 64) return;
    int n = i >> 6, j = i & 63;
    float p = (float)pos[n];
    float ang = p * powf(10000.f, -(float)j * (1.0f / 64.0f));
    tab[i] = make_float2(cosf(ang), sinf(ang));
}

// RoPE on Q and K (both inside QKV, row stride ld), one dispatch
__global__ void rope_apply2(__hip_bfloat16* __restrict__ Q, __hip_bfloat16* __restrict__ K,
                            const float2* __restrict__ tab, int ld)
{
    int i = blockIdx.x * 256 + threadIdx.x;     // 8192 rows x 256 chunks
    __hip_bfloat16* T = blockIdx.y ? K : Q;
    int r  = i >> 8;
    int cb = (i & 255) << 3;
    int n  = r & 2047;
    int j0 = (cb >> 1) & 63;
    union { bf16x8 v; __hip_bfloat162 h[4]; } u;
    __hip_bfloat16* p = T + (size_t)r * ld + cb;
    u.v = *(const bf16x8*)p;
#pragma unroll
    for (int k = 0; k < 4; ++k) {
        float2 cs = tab[(n << 6) + j0 + k];
        float x1 = __bfloat162float(u.h[k].x);
        float x2 = __bfloat162float(u.h[k].y);
        u.h[k].x = __float2bfloat16(cs.x * x1 - cs.y * x2);
        u.h[k].y = __float2bfloat16(cs.y * x1 + cs.x * x2);
    }
    *(bf16x8*)p = u.v;
}

// ---------------------------------------------------------------------------
__global__ void softmax_causal_ip(float* __restrict__ S, int N)
{
    const int q = blockIdx.x;
    float* srow = S + ((size_t)blockIdx.y * N + q) * N;
    __shared__ float buf[2048];
    __shared__ float red[8];
    const int tid = threadIdx.x;

    float4* b4 = (float4*)buf;
    const float4* s4 = (const float4*)srow;
    for (int i = tid; i < N / 4; i += 256) b4[i] = s4[i];
    __syncthreads();

    float m = -1e30f;
    for (int j = tid; j <= q; j += 256) m = fmaxf(m, buf[j]);
#pragma unroll
    for (int o = 32; o > 0; o >>= 1) m = fmaxf(m, __shfl_xor(m, o));
    if ((tid & 63) == 0) red[tid >> 6] = m;
    __syncthreads();
    m = fmaxf(fmaxf(red[0], red[1]), fmaxf(red[2], red[3]));

    float sum = 0.f;
    for (int j = tid; j <= q; j += 256) { float e = __expf(buf[j] - m); buf[j] = e; sum += e; }
#pragma unroll
    for (int o = 32; o > 0; o >>= 1) sum += __shfl_xor(sum, o);
    if ((tid & 63) == 0) red[4 + (tid >> 6)] = sum;
    __syncthreads();
    const float inv = 1.f / (red[4] + red[5] + red[6] + red[7]);

    __hip_bfloat162* p2 = (__hip_bfloat162*)srow;
    for (int i = tid; i < N / 2; i += 256) {
        int j0 = i * 2;
        __hip_bfloat162 h;
        h.x = __float2bfloat16(j0     <= q ? buf[j0]     * inv : 0.f);
        h.y = __float2bfloat16(j0 + 1 <= q ? buf[j0 + 1] * inv : 0.f);
        p2[i] = h;
    }
}

// Vt[b][d][k] = V[b][k][d]; V has row stride ldv (inside QKV)
__global__ void transpose_bf16(const __hip_bfloat16* __restrict__ V,
                               __hip_bfloat16* __restrict__ Vt, int N, int ldv)
{
    __shared__ __hip_bfloat16 tile[32][33];
    const size_t bi = (size_t)blockIdx.z * N * ldv;
    const size_t bo = (size_t)blockIdx.z * N * N;
    const int k0 = blockIdx.x * 32, d0 = blockIdx.y * 32;
    const int tx = threadIdx.x, ty = threadIdx.y;   // 32 x 8
#pragma unroll
    for (int j = 0; j < 4; ++j)
        tile[ty + 8 * j][tx] = V[bi + (size_t)(k0 + ty + 8 * j) * ldv + d0 + tx];
    __syncthreads();
#pragma unroll
    for (int j = 0; j < 4; ++j)
        Vt[bo + (size_t)(d0 + ty + 8 * j) * N + k0 + tx] = tile[tx][ty + 8 * j];
}

// ---------------------------------------------------------------------------
extern "C" void kernel_launch(void* const* d_in, const int* in_sizes, int n_in,
                              void* d_out, int out_size, void* d_ws, size_t ws_size,
                              hipStream_t stream)
{
    const float* x  = (const float*)d_in[0];
    const int* pos  = (const int*)d_in[1];
    const float* wq = (const float*)d_in[2];
    const float* wk = (const float*)d_in[3];
    const float* wv = (const float*)d_in[4];
    const float* wo = (const float*)d_in[5];
    float* out = (float*)d_out;

    const int B = 4, N = 2048, D = 2048;
    const int M = B * N;                      // 8192
    const int D3 = 3 * D;                     // 6144
    const size_t MB = 1ull << 20;
    if (ws_size < 192 * MB) return;

    char* w = (char*)d_ws;
    __hip_bfloat16* QKV  = (__hip_bfloat16*)(w + 0 * MB);    // 96 MB, ld 6144
    __hip_bfloat16* wqkv = (__hip_bfloat16*)(w + 96 * MB);   // 24 MB
    __hip_bfloat16* wob  = (__hip_bfloat16*)(w + 120 * MB);  //  8 MB
    __hip_bfloat16* xb   = (__hip_bfloat16*)(w + 128 * MB);  // 32 MB, dead after QKV GEMM
    __hip_bfloat16* Vt   = xb;                               // alias
    __hip_bfloat16* AO   = (__hip_bfloat16*)(w + 160 * MB);  // 32 MB
    float2*         tab  = (float2*)(w + 190 * MB);          //  1 MB

    __hip_bfloat16* Qb = QKV;
    __hip_bfloat16* Kb = QKV + D;       // col offset 2048
    __hip_bfloat16* Vb = QKV + 2 * D;   // col offset 4096

    float* Sal = (float*)d_out;         // S for all 4 batches = 64MB = d_out

    // 1. converts + RoPE table
    f32_to_bf16_vec<<<(M * D / 4 + 255) / 256, 256, 0, stream>>>(x, xb, M * D / 4);
    conv_w4<<<dim3((D * D / 4 + 255) / 256, 4), 256, 0, stream>>>(
        wq, wk, wv, wo, wqkv, wqkv + (size_t)D * D, wqkv + (size_t)2 * D * D, wob, D * D / 4);
    rope_table<<<(N * 64 + 255) / 256, 256, 0, stream>>>(pos, tab, N);

    // 2. fused QKV projection: C[8192 x 6144], 768 wgs
    gemm256<__hip_bfloat16><<<dim3((D3 / 256) * (M / 256)), 512, 0, stream>>>(
        xb, wqkv, QKV, D, D, D, D3, D3 / 256, 1.f);

    // 3. RoPE on Q and K
    rope_apply2<<<dim3(M, 2), 256, 0, stream>>>(Qb, Kb, tab, D3);

    // 4. V transpose (Vt aliases dead xb)
    transpose_bf16<<<dim3(N / 32, N / 32, B), dim3(32, 8), 0, stream>>>(Vb, Vt, N, D3);

    // 5. attention
    const float scale = 1.0f / sqrtf((float)D);
    gemm128<float, 1><<<dim3(72, B), 512, 0, stream>>>(
        Qb, Kb, Sal, D, D3, D3, N, N / 256, scale,
        (size_t)N * D3, (size_t)N * D3, (size_t)N * N);
    softmax_causal_ip<<<dim3(N, B), 256, 0, stream>>>(Sal, N);
    gemm128<__hip_bfloat16, 2><<<dim3((N / 128) * (N / 256), B), 512, 0, stream>>>(
        (const __hip_bfloat16*)Sal, Vt, AO, N, 2 * N, N, D, N / 256, 1.f,
        (size_t)2 * N * N, (size_t)N * N, (size_t)N * D);

    // 6. output projection
    gemm256<float><<<dim3((D / 256) * (M / 256)), 512, 0, stream>>>(
        AO, wob, out, D, D, D, D, D / 256, 1.f);
}

// Round 10
// 463.073 us; speedup vs baseline: 1.1006x; 1.1006x over previous
//
#include <hip/hip_runtime.h>
#include <hip/hip_bf16.h>
#include <cstdint>
#include <cmath>

typedef __attribute__((ext_vector_type(4))) float f32x4;
typedef __attribute__((ext_vector_type(8))) short bf16x8;

#define BAR()   __builtin_amdgcn_s_barrier()
#define PRIO1() __builtin_amdgcn_s_setprio(1)
#define PRIO0() __builtin_amdgcn_s_setprio(0)
#define WAITV6() asm volatile("s_waitcnt vmcnt(6)" ::: "memory")
#define WAITV4() asm volatile("s_waitcnt vmcnt(4)" ::: "memory")
#define WAITV0() asm volatile("s_waitcnt vmcnt(0)" ::: "memory")
#define MM(a,b,c) __builtin_amdgcn_mfma_f32_16x16x32_bf16((a),(b),(c),0,0,0)

__device__ __forceinline__ void gl_lds16(const __hip_bfloat16* g, char* l) {
    __builtin_amdgcn_global_load_lds(
        (const __attribute__((address_space(1))) void*)g,
        (__attribute__((address_space(3))) void*)l, 16, 0, 0);
}
__device__ __forceinline__ void store_c(float* C, size_t i, float v) { C[i] = v; }
__device__ __forceinline__ void store_c(__hip_bfloat16* C, size_t i, float v) { C[i] = __float2bfloat16(v); }

// ===========================================================================
// gemm8p (v2, group-fixed): 256x256 tile, BK=64, 8 waves (2Mx4N, wave out
// 128x64), 2 dbuf x 64KB = 128KB LDS. 4 phases/K-tile, snake quadrants
// (mL,nL)->(mL,nH)->(mH,nH)->(mH,nL); per phase {ds_read frags || stage one
// GROUP} BAR; prio1; 16 MFMA; prio0; BAR.
//
// KEY FIX vs R9: stage groups = PHASE READ-SETS (union over waves), not
// geometric halves:
//   A0 = subtiles read in ph1 = {wr*16 + 0..7}  = units (h,i=0), h=0,1
//   A1 = read in ph3         = {wr*16 + 8..15} = units (h,i=1)
//   B relabeled: sB = (ni>>1)*16 + wc*4 + (ni&1)*2 + kk, so
//   B0 = ph1/ph4 read-set = sB [0,16) = units g0,g1; B1 = ph2 = [16,32).
// Stage schedule (each lands right after its group's last read, WAR-safe
// via the phase end-BAR):
//   t.ph1: B0(t+1) -> buf d^1     [buf e's B0 last read at t-1.ph4]
//   t.ph2: A0(t+2) -> buf d       [A0(d) last read t.ph1]
//   t.ph3: B1(t+2) -> buf d       [B1(d) last read t.ph2]
//   t.ph4: A1(t+2) -> buf d       [A1(d) last read t.ph3]
// vmcnt(6) ONCE per tile at ph4: in-flight 14 = {A0,B1,A1}(t+1)[6 from t-1]
// + B0(t+1)[t.ph1] + {A0,B1,A1}(t+2)[6]; keep newest 6 -> drains all of
// t+1's groups. 7-phase prefetch lead. Prologue: tile0 all 4 groups +
// {A0,B1,A1}(1); vmcnt(6); BAR. Tail: t+2>=nt -> no stage, vmcnt(0).
// Fragment/swizzle maps identical to the R3/R4-proven ones.
// ===========================================================================
#define SGA8(dd, h, i, kt) do{ const int s_ = (h)*16 + (i)*8 + w; \
    gl_lds16(Asb + (size_t)((s_>>1)<<4) * lda + ((s_&1)<<5) + (kt), \
             lds + (dd)*65536 + (s_<<10)); }while(0)
#define SGB8N(dd, g, kt) do{ const int sB_ = (g)*8 + w; \
    const int hi_ = sB_ >> 4, r_ = sB_ & 15; \
    const int wc_ = r_ >> 2, ni_ = hi_*2 + ((r_>>1)&1), kk_ = r_ & 1; \
    gl_lds16(Bsb + (size_t)(wc_*64 + ni_*16) * ldb + (kk_<<5) + (kt), \
             lds + (dd)*65536 + 32768 + (sB_<<10)); }while(0)
#define LDA8(dd, miA, kk) (*(const bf16x8*)(lds + (dd)*65536 + ((sbA + (miA)*2 + (kk)) << 10) + rswz))
#define LDB8N(dd, ni, kk) (*(const bf16x8*)(lds + (dd)*65536 + 32768 + \
    ((((((ni)>>1)<<4) + ((w&3)<<2) + (((ni)&1)<<1) + (kk))) << 10) + rswz))

template<typename CT>
__global__ __launch_bounds__(512, 2)
void gemm8p(const __hip_bfloat16* __restrict__ A, const __hip_bfloat16* __restrict__ B,
            CT* __restrict__ C, int K, int lda, int ldb, int ldc, int nbx, float alpha)
{
    __shared__ __align__(1024) char lds[131072];

    // bijective XCD-aware swizzle (m204)
    const int nwg = gridDim.x;
    const int q8 = nwg >> 3, r8 = nwg & 7;
    const int xcd = blockIdx.x & 7, blk = blockIdx.x >> 3;
    const int wg = (xcd < r8 ? xcd * (q8 + 1) : r8 * (q8 + 1) + (xcd - r8) * q8) + blk;
    const int bm0 = (wg / nbx) * 256, bn0 = (wg % nbx) * 256;

    const int tid  = threadIdx.x;
    const int lane = tid & 63;
    const int w    = tid >> 6;

    const int rb   = (lane & 15) * 64 + (lane >> 4) * 16;
    const int rswz = rb ^ (((rb >> 9) & 1) << 5);
    const int sbA  = (w >> 2) * 16;

    const int l16 = lane * 16;
    const int uqs = l16 ^ (((l16 >> 9) & 1) << 5);
    const int rIn = uqs >> 6;
    const int cIn = (uqs & 63) >> 1;
    const __hip_bfloat16* Asb = A + (size_t)(bm0 + rIn) * lda + cIn;
    const __hip_bfloat16* Bsb = B + (size_t)(bn0 + rIn) * ldb + cIn;

    f32x4 acc[8][4] = {};
    bf16x8 afA[4][2], bfB[2][2];

    const int nt = K >> 6;              // 32 for K=2048

    // prologue: tile0 groups A0,B0,B1,A1 then tile1 {A0,B1,A1}
    SGA8(0, 0, 0, 0); SGA8(0, 1, 0, 0);            // A0(0)
    SGB8N(0, 0, 0);   SGB8N(0, 1, 0);              // B0(0)
    SGB8N(0, 2, 0);   SGB8N(0, 3, 0);              // B1(0)
    SGA8(0, 0, 1, 0); SGA8(0, 1, 1, 0);            // A1(0)
    if (nt > 1) {
        SGA8(1, 0, 0, 64); SGA8(1, 1, 0, 64);      // A0(1)
        SGB8N(1, 2, 64);   SGB8N(1, 3, 64);        // B1(1)
        SGA8(1, 0, 1, 64); SGA8(1, 1, 1, 64);      // A1(1)
        WAITV6();
    } else WAITV0();
    BAR();

    for (int t = 0; t < nt; ++t) {
        const int d   = t & 1, e = d ^ 1;
        const bool p1 = (t + 1) < nt;
        const bool p2 = (t + 2) < nt;
        const int kt1 = (t + 1) << 6;
        const int kt2 = (t + 2) << 6;

        // ---- ph1: (mLow, nLow). read A0-frags + B0-frags; stage B0(t+1)->e
#pragma unroll
        for (int mi = 0; mi < 4; ++mi) { afA[mi][0] = LDA8(d, mi, 0); afA[mi][1] = LDA8(d, mi, 1); }
#pragma unroll
        for (int ni = 0; ni < 2; ++ni) { bfB[ni][0] = LDB8N(d, ni, 0); bfB[ni][1] = LDB8N(d, ni, 1); }
        if (p1) { SGB8N(e, 0, kt1); SGB8N(e, 1, kt1); }
        BAR();
        PRIO1();
#pragma unroll
        for (int mi = 0; mi < 4; ++mi)
#pragma unroll
            for (int ni = 0; ni < 2; ++ni) {
                f32x4 c = acc[mi][ni];
                c = MM(afA[mi][0], bfB[ni][0], c);
                c = MM(afA[mi][1], bfB[ni][1], c);
                acc[mi][ni] = c;
            }
        PRIO0();
        BAR();

        // ---- ph2: (mLow, nHigh). read B1-frags; stage A0(t+2)->d
#pragma unroll
        for (int ni = 0; ni < 2; ++ni) { bfB[ni][0] = LDB8N(d, 2 + ni, 0); bfB[ni][1] = LDB8N(d, 2 + ni, 1); }
        if (p2) { SGA8(d, 0, 0, kt2); SGA8(d, 1, 0, kt2); }
        BAR();
        PRIO1();
#pragma unroll
        for (int mi = 0; mi < 4; ++mi)
#pragma unroll
            for (int ni = 0; ni < 2; ++ni) {
                f32x4 c = acc[mi][2 + ni];
                c = MM(afA[mi][0], bfB[ni][0], c);
                c = MM(afA[mi][1], bfB[ni][1], c);
                acc[mi][2 + ni] = c;
            }
        PRIO0();
        BAR();

        // ---- ph3: (mHigh, nHigh). read A1-frags; stage B1(t+2)->d
#pragma unroll
        for (int mi = 0; mi < 4; ++mi) { afA[mi][0] = LDA8(d, 4 + mi, 0); afA[mi][1] = LDA8(d, 4 + mi, 1); }
        if (p2) { SGB8N(d, 2, kt2); SGB8N(d, 3, kt2); }
        BAR();
        PRIO1();
#pragma unroll
        for (int mi = 0; mi < 4; ++mi)
#pragma unroll
            for (int ni = 0; ni < 2; ++ni) {
                f32x4 c = acc[4 + mi][2 + ni];
                c = MM(afA[mi][0], bfB[ni][0], c);
                c = MM(afA[mi][1], bfB[ni][1], c);
                acc[4 + mi][2 + ni] = c;
            }
        PRIO0();
        BAR();

        // ---- ph4: (mHigh, nLow). re-read B0-frags; stage A1(t+2)->d; vmcnt
#pragma unroll
        for (int ni = 0; ni < 2; ++ni) { bfB[ni][0] = LDB8N(d, ni, 0); bfB[ni][1] = LDB8N(d, ni, 1); }
        if (p2) { SGA8(d, 0, 1, kt2); SGA8(d, 1, 1, kt2); WAITV6(); }
        else WAITV0();
        BAR();
        PRIO1();
#pragma unroll
        for (int mi = 0; mi < 4; ++mi)
#pragma unroll
            for (int ni = 0; ni < 2; ++ni) {
                f32x4 c = acc[4 + mi][ni];
                c = MM(afA[mi][0], bfB[ni][0], c);
                c = MM(afA[mi][1], bfB[ni][1], c);
                acc[4 + mi][ni] = c;
            }
        PRIO0();
        BAR();
    }

    // epilogue: C/D layout col=lane&15, row=(lane>>4)*4+j (m89/m91)
    const int cr = (lane >> 4) * 4, cc = lane & 15;
    const int wrow = bm0 + (w >> 2) * 128, wcol = bn0 + (w & 3) * 64;
#pragma unroll
    for (int mi = 0; mi < 8; ++mi)
#pragma unroll
        for (int ni = 0; ni < 4; ++ni) {
            const int row = wrow + mi * 16 + cr;
            const int col = wcol + ni * 16 + cc;
#pragma unroll
            for (int j = 0; j < 4; ++j)
                store_c(C, (size_t)(row + j) * ldc + col, acc[mi][ni][j] * alpha);
        }
}

// ===========================================================================
// gemm256 — R4-proven (479.6 µs run): 256x256, BK=32, 8 waves, 3-buffer
// 96KB LDS, 2-tile prefetch, counted vmcnt(4), 3 BAR/tile.
// MODE 0: dense + XCD swizzle. MODE 1: causal S triangular (grid 36/batch).
// MODE 2: PV, kend=bm0+256, diagonal-shifted mapping.
// ===========================================================================
#define STAGEA(nb, kt) do{ gl_lds16(Asrc + (kt),                        lds + (nb)         + wb); \
                           gl_lds16(Asrc + (size_t)128 * lda + (kt),    lds + (nb) +  8192 + wb);}while(0)
#define STAGEB(nb, kt) do{ gl_lds16(Bsrc + (kt),                        lds + (nb) + 16384 + wb); \
                           gl_lds16(Bsrc + (size_t)128 * ldb + (kt),    lds + (nb) + 24576 + wb);}while(0)

template<typename CT, int MODE>
__global__ __launch_bounds__(512, 2)
void gemm256(const __hip_bfloat16* __restrict__ A, const __hip_bfloat16* __restrict__ B,
             CT* __restrict__ C, int K, int lda, int ldb, int ldc, int nbx,
             float alpha, size_t sA, size_t sB, size_t sC)
{
    __shared__ __align__(1024) char lds[98304];

    int bm0, bn0;
    if (MODE == 1) {
        const int wgi = blockIdx.x;
        int by = (int)((sqrtf(8.f * wgi + 1.f) - 1.f) * 0.5f);
        if (by * (by + 1) / 2 > wgi) --by;
        if ((by + 1) * (by + 2) / 2 <= wgi) ++by;
        const int bx = wgi - by * (by + 1) / 2;
        bm0 = by * 256; bn0 = bx * 256;
    } else if (MODE == 2) {
        const int g = blockIdx.x;
        const int nby = gridDim.x / nbx;
        const int bx = g % nbx;
        const int by = (g / nbx + bx) % nby;
        bm0 = by * 256; bn0 = bx * 256;
    } else {
        const int nwg = gridDim.x;
        const int q8 = nwg >> 3, r8 = nwg & 7;
        const int xcd = blockIdx.x & 7, blk = blockIdx.x >> 3;
        const int wg = (xcd < r8 ? xcd * (q8 + 1) : r8 * (q8 + 1) + (xcd - r8) * q8) + blk;
        bm0 = (wg / nbx) * 256; bn0 = (wg % nbx) * 256;
    }

    A += sA * blockIdx.y; B += sB * blockIdx.y; C += sC * blockIdx.y;

    const int tid  = threadIdx.x;
    const int lane = tid & 63;
    const int w    = tid >> 6;
    const int wb   = w * 1024;

    const int rb   = (lane & 15) * 64 + (lane >> 4) * 16;
    const int rswz = rb ^ (((rb >> 9) & 1) << 5);
    const int srA  = (w >> 2) * 8;
    const int srB  = (w & 3) * 4;

    const int q0 = tid * 16;
    const int uq = q0 ^ (((q0 >> 9) & 1) << 5);
    const int r0 = ((q0 >> 10) << 4) | ((uq >> 6) & 15);
    const int c0 = (uq & 63) >> 1;
    const __hip_bfloat16* Asrc = A + (size_t)(bm0 + r0) * lda + c0;
    const __hip_bfloat16* Bsrc = B + (size_t)(bn0 + r0) * ldb + c0;

    f32x4 acc[8][4] = {};
    bf16x8 af[4], bf[4];

    const int klim = bm0 + 256;
    const int kend = (MODE == 2) ? (K < klim ? K : klim) : K;
    const int nt   = kend >> 5;

    STAGEA(0, 0); STAGEB(0, 0);
    if (nt > 1) { STAGEA(32768, 32); STAGEB(32768, 32); }

    for (int t = 0; t < nt; ++t) {
        if (t + 1 < nt) WAITV4(); else WAITV0();
        BAR();
        const char* dA = lds + (t % 3) * 32768;
        const char* dB = dA + 16384;
        const int  nbo = ((t + 2) % 3) * 32768;
        const bool pf  = (t + 2 < nt);
        const int  kt  = (t + 2) << 5;

#pragma unroll
        for (int i = 0; i < 4; ++i) af[i] = *(const bf16x8*)(dA + ((srA + i) << 10) + rswz);
#pragma unroll
        for (int i = 0; i < 4; ++i) bf[i] = *(const bf16x8*)(dB + ((srB + i) << 10) + rswz);
        if (pf) STAGEA(nbo, kt);
        BAR();
        PRIO1();
#pragma unroll
        for (int mi = 0; mi < 4; ++mi)
#pragma unroll
            for (int ni = 0; ni < 4; ++ni)
                acc[mi][ni] = MM(af[mi], bf[ni], acc[mi][ni]);
        PRIO0();

#pragma unroll
        for (int i = 0; i < 4; ++i) af[i] = *(const bf16x8*)(dA + ((srA + 4 + i) << 10) + rswz);
        if (pf) STAGEB(nbo, kt);
        BAR();
        PRIO1();
#pragma unroll
        for (int mi = 0; mi < 4; ++mi)
#pragma unroll
            for (int ni = 0; ni < 4; ++ni)
                acc[4 + mi][ni] = MM(af[mi], bf[ni], acc[4 + mi][ni]);
        PRIO0();
    }

    const int cr = (lane >> 4) * 4, cc = lane & 15;
    const int wrow = bm0 + (w >> 2) * 128, wcol = bn0 + (w & 3) * 64;
#pragma unroll
    for (int mi = 0; mi < 8; ++mi)
#pragma unroll
        for (int ni = 0; ni < 4; ++ni) {
            const int row = wrow + mi * 16 + cr;
            const int col = wcol + ni * 16 + cc;
#pragma unroll
            for (int j = 0; j < 4; ++j)
                store_c(C, (size_t)(row + j) * ldc + col, acc[mi][ni][j] * alpha);
        }
}

// ---------------------------------------------------------------------------
__global__ void f32_to_bf16_vec(const float* __restrict__ in,
                                __hip_bfloat16* __restrict__ out, int n4)
{
    int i = blockIdx.x * 256 + threadIdx.x;
    if (i >= n4) return;
    float4 v = ((const float4*)in)[i];
    union { ushort4 u; __hip_bfloat16 h[4]; } o;
    o.h[0] = __float2bfloat16(v.x);
    o.h[1] = __float2bfloat16(v.y);
    o.h[2] = __float2bfloat16(v.z);
    o.h[3] = __float2bfloat16(v.w);
    ((ushort4*)out)[i] = o.u;
}

__global__ void conv_w4(const float* __restrict__ w0, const float* __restrict__ w1,
                        const float* __restrict__ w2, const float* __restrict__ w3,
                        __hip_bfloat16* o0, __hip_bfloat16* o1,
                        __hip_bfloat16* o2, __hip_bfloat16* o3, int n4)
{
    int i = blockIdx.x * 256 + threadIdx.x;
    if (i >= n4) return;
    const float* src; __hip_bfloat16* dst;
    switch (blockIdx.y) {
        case 0: src = w0; dst = o0; break;
        case 1: src = w1; dst = o1; break;
        case 2: src = w2; dst = o2; break;
        default: src = w3; dst = o3; break;
    }
    float4 v = ((const float4*)src)[i];
    union { ushort4 u; __hip_bfloat16 h[4]; } o;
    o.h[0] = __float2bfloat16(v.x);
    o.h[1] = __float2bfloat16(v.y);
    o.h[2] = __float2bfloat16(v.z);
    o.h[3] = __float2bfloat16(v.w);
    ((ushort4*)dst)[i] = o.u;
}

__global__ void rope_table(const int* __restrict__ pos, float2* __restrict__ tab, int N)
{
    int i = blockIdx.x * 256 + threadIdx.x;
    if (i >= N * 64) return;
    int n = i >> 6, j = i & 63;
    float p = (float)pos[n];
    float ang = p * powf(10000.f, -(float)j * (1.0f / 64.0f));
    tab[i] = make_float2(cosf(ang), sinf(ang));
}

__global__ void rope_apply2(__hip_bfloat16* __restrict__ Q, __hip_bfloat16* __restrict__ K,
                            const float2* __restrict__ tab, int ld)
{
    int i = blockIdx.x * 256 + threadIdx.x;
    __hip_bfloat16* T = blockIdx.y ? K : Q;
    int r  = i >> 8;
    int cb = (i & 255) << 3;
    int n  = r & 2047;
    int j0 = (cb >> 1) & 63;
    union { bf16x8 v; __hip_bfloat162 h[4]; } u;
    __hip_bfloat16* p = T + (size_t)r * ld + cb;
    u.v = *(const bf16x8*)p;
#pragma unroll
    for (int k = 0; k < 4; ++k) {
        float2 cs = tab[(n << 6) + j0 + k];
        float x1 = __bfloat162float(u.h[k].x);
        float x2 = __bfloat162float(u.h[k].y);
        u.h[k].x = __float2bfloat16(cs.x * x1 - cs.y * x2);
        u.h[k].y = __float2bfloat16(cs.y * x1 + cs.x * x2);
    }
    *(bf16x8*)p = u.v;
}

// ---------------------------------------------------------------------------
// In-place causal softmax, extent-trimmed: reads cols [0,q], writes bf16 P
// only up to the 256-block boundary wend = ((q>>8)+1)*256 (PV's klim
// guarantees cols >= wend are never read).
// ---------------------------------------------------------------------------
__global__ void softmax_causal_ip(float* __restrict__ S, int N)
{
    const int q = blockIdx.x;
    float* srow = S + ((size_t)blockIdx.y * N + q) * N;
    __shared__ float buf[2048];
    __shared__ float red[8];
    const int tid = threadIdx.x;
    const int wend = ((q >> 8) + 1) << 8;

    float4* b4 = (float4*)buf;
    const float4* s4 = (const float4*)srow;
    for (int i = tid; i <= (q >> 2); i += 256) b4[i] = s4[i];
    __syncthreads();

    float m = -1e30f;
    for (int j = tid; j <= q; j += 256) m = fmaxf(m, buf[j]);
#pragma unroll
    for (int o = 32; o > 0; o >>= 1) m = fmaxf(m, __shfl_xor(m, o));
    if ((tid & 63) == 0) red[tid >> 6] = m;
    __syncthreads();
    m = fmaxf(fmaxf(red[0], red[1]), fmaxf(red[2], red[3]));

    float sum = 0.f;
    for (int j = tid; j <= q; j += 256) { float e = __expf(buf[j] - m); buf[j] = e; sum += e; }
#pragma unroll
    for (int o = 32; o > 0; o >>= 1) sum += __shfl_xor(sum, o);
    if ((tid & 63) == 0) red[4 + (tid >> 6)] = sum;
    __syncthreads();
    const float inv = 1.f / (red[4] + red[5] + red[6] + red[7]);

    __hip_bfloat162* p2 = (__hip_bfloat162*)srow;
    for (int i = tid; i < (wend >> 1); i += 256) {
        int j0 = i * 2;
        __hip_bfloat162 h;
        h.x = __float2bfloat16(j0     <= q ? buf[j0]     * inv : 0.f);
        h.y = __float2bfloat16(j0 + 1 <= q ? buf[j0 + 1] * inv : 0.f);
        p2[i] = h;
    }
}

// Vt[b][d][k] = V[b][k][d]; V row stride ldv (inside QKV)
__global__ void transpose_bf16(const __hip_bfloat16* __restrict__ V,
                               __hip_bfloat16* __restrict__ Vt, int N, int ldv)
{
    __shared__ __hip_bfloat16 tile[32][33];
    const size_t bi = (size_t)blockIdx.z * N * ldv;
    const size_t bo = (size_t)blockIdx.z * N * N;
    const int k0 = blockIdx.x * 32, d0 = blockIdx.y * 32;
    const int tx = threadIdx.x, ty = threadIdx.y;   // 32 x 8
#pragma unroll
    for (int j = 0; j < 4; ++j)
        tile[ty + 8 * j][tx] = V[bi + (size_t)(k0 + ty + 8 * j) * ldv + d0 + tx];
    __syncthreads();
#pragma unroll
    for (int j = 0; j < 4; ++j)
        Vt[bo + (size_t)(d0 + ty + 8 * j) * N + k0 + tx] = tile[tx][ty + 8 * j];
}

// ---------------------------------------------------------------------------
extern "C" void kernel_launch(void* const* d_in, const int* in_sizes, int n_in,
                              void* d_out, int out_size, void* d_ws, size_t ws_size,
                              hipStream_t stream)
{
    const float* x  = (const float*)d_in[0];
    const int* pos  = (const int*)d_in[1];
    const float* wq = (const float*)d_in[2];
    const float* wk = (const float*)d_in[3];
    const float* wv = (const float*)d_in[4];
    const float* wo = (const float*)d_in[5];
    float* out = (float*)d_out;

    const int B = 4, N = 2048, D = 2048;
    const int M = B * N;                      // 8192
    const int D3 = 3 * D;                     // 6144
    const size_t MB = 1ull << 20;
    if (ws_size < 192 * MB) return;

    char* w = (char*)d_ws;
    __hip_bfloat16* QKV  = (__hip_bfloat16*)(w + 0 * MB);    // 96 MB, ld 6144
    __hip_bfloat16* wqkv = (__hip_bfloat16*)(w + 96 * MB);   // 24 MB
    __hip_bfloat16* wob  = (__hip_bfloat16*)(w + 120 * MB);  //  8 MB
    __hip_bfloat16* xb   = (__hip_bfloat16*)(w + 128 * MB);  // 32 MB, dead after QKV GEMM
    __hip_bfloat16* Vt   = xb;                               // alias
    __hip_bfloat16* AO   = (__hip_bfloat16*)(w + 160 * MB);  // 32 MB
    float2*         tab  = (float2*)(w + 190 * MB);          //  1 MB

    __hip_bfloat16* Qb = QKV;
    __hip_bfloat16* Kb = QKV + D;
    __hip_bfloat16* Vb = QKV + 2 * D;

    float* Sal = (float*)d_out;              // S scratch = d_out (64 MB)

    // 1. converts + RoPE table
    f32_to_bf16_vec<<<(M * D / 4 + 255) / 256, 256, 0, stream>>>(x, xb, M * D / 4);
    conv_w4<<<dim3((D * D / 4 + 255) / 256, 4), 256, 0, stream>>>(
        wq, wk, wv, wo, wqkv, wqkv + (size_t)D * D, wqkv + (size_t)2 * D * D, wob, D * D / 4);
    rope_table<<<(N * 64 + 255) / 256, 256, 0, stream>>>(pos, tab, N);

    // 2. fused QKV projection on gemm8p (EXPERIMENT, 768 wgs)
    gemm8p<__hip_bfloat16><<<dim3((D3 / 256) * (M / 256)), 512, 0, stream>>>(
        xb, wqkv, QKV, D, D, D, D3, D3 / 256, 1.f);

    // 3. RoPE on Q and K
    rope_apply2<<<dim3(M, 2), 256, 0, stream>>>(Qb, Kb, tab, D3);

    // 4. V transpose (Vt aliases dead xb)
    transpose_bf16<<<dim3(N / 32, N / 32, B), dim3(32, 8), 0, stream>>>(Vb, Vt, N, D3);

    // 5. attention — R4-proven gemm256 MODE1/MODE2
    const float scale = 1.0f / sqrtf((float)D);
    const int nbxA = N / 256;                           // 8
    const int ntri = nbxA * (nbxA + 1) / 2;             // 36
    gemm256<float, 1><<<dim3(ntri, B), 512, 0, stream>>>(
        Qb, Kb, Sal, D, D3, D3, N, nbxA, scale,
        (size_t)N * D3, (size_t)N * D3, (size_t)N * N);
    softmax_causal_ip<<<dim3(N, B), 256, 0, stream>>>(Sal, N);
    gemm256<__hip_bfloat16, 2><<<dim3(nbxA * nbxA, B), 512, 0, stream>>>(
        (const __hip_bfloat16*)Sal, Vt, AO, N, 2 * N, N, D, nbxA, 1.f,
        (size_t)2 * N * N, (size_t)N * N, (size_t)N * D);

    // 6. output projection (control: gemm256 MODE0)
    gemm256<float, 0><<<dim3((D / 256) * (M / 256)), 512, 0, stream>>>(
        AO, wob, out, D, D, D, D, D / 256, 1.f, 0, 0, 0);
}

// Round 11
// 461.769 us; speedup vs baseline: 1.1038x; 1.0028x over previous
//
#include <hip/hip_runtime.h>
#include <hip/hip_bf16.h>
#include <cstdint>
#include <cmath>

typedef __attribute__((ext_vector_type(4))) float f32x4;
typedef __attribute__((ext_vector_type(8))) short bf16x8;

#define BAR()   __builtin_amdgcn_s_barrier()
#define PRIO1() __builtin_amdgcn_s_setprio(1)
#define PRIO0() __builtin_amdgcn_s_setprio(0)
#define WAITV8() asm volatile("s_waitcnt vmcnt(8)" ::: "memory")
#define WAITV6() asm volatile("s_waitcnt vmcnt(6)" ::: "memory")
#define WAITV0() asm volatile("s_waitcnt vmcnt(0)" ::: "memory")
#define MM(a,b,c) __builtin_amdgcn_mfma_f32_16x16x32_bf16((a),(b),(c),0,0,0)

__device__ __forceinline__ void gl_lds16(const __hip_bfloat16* g, char* l) {
    __builtin_amdgcn_global_load_lds(
        (const __attribute__((address_space(1))) void*)g,
        (__attribute__((address_space(3))) void*)l, 16, 0, 0);
}
__device__ __forceinline__ void store_c(float* C, size_t i, float v) { C[i] = v; }
__device__ __forceinline__ void store_c(__hip_bfloat16* C, size_t i, float v) { C[i] = __float2bfloat16(v); }

// ===========================================================================
// gemm8p v3 — pre-read pipeline. 256x256 tile, BK=64, 8 waves (2Mx4N, wave
// out 128x64), 2 dbuf x 64KB = 128KB LDS. 4 phases/K-tile; EVERY fragment is
// ds_read one phase EARLY, inside the previous MFMA window, so each window =
// 16 MFMA || <=8 independent ds_reads (LDS pipe never idles during MFMA).
// B0 frags live in regs ph1->ph4 (no re-read): 24 reads/tile at 4/8/8/4.
//
// Groups (= phase read-sets, R10-proven): A0 = LDS subtiles {wr*16+0..7},
// A1 = {wr*16+8..15}; B relabeled sB = (ni>>1)*16 + wc*4 + (ni&1)*2 + kk:
// B0 = sB[0,16) (used ph1+ph4), B1 = sB[16,32) (ph2+ph3).
// Stage schedule: t.ph1: B0(t+1)->e; ph2: A0(t+2)->d; ph3: B1(t+2)->d;
// ph4: A1(t+2)->d  (each lands right after its group's last read; WAR-safe
// via phase end-BAR; A0(d)'s last read moved to t-1.ph3 — stage at t.ph2 ok).
// vmcnt ledger (issue order: A0(t+1),B1(t+1),A1(t+1) [t-1.ph2/3/4],
// B0(t+1) [t.ph1], A0(t+2) [t.ph2], B1(t+2) [t.ph3], A1(t+2) [t.ph4]):
//   ph2 WAITV8: in-flight 10, keep 8 -> drains A0(t+1)  => ph3 read-ahead ok
//   ph4 WAITV6: in-flight 12, keep {A0,B1,A1}(t+2)      => drains B1/A1/B0(t+1)
// Window reads: ph1: B1cur(4); ph2: A1cur(8); ph3: A0next(8, buf e);
// ph4: B0next(4, buf e). Tails: ph2 = p2?V8 : p1?V6 : V0; ph4 = p2?V6 : V0;
// read-aheads guarded by p1. Prologue: t0 all(8) + t1{A0,B1,A1}(6); WAITV6;
// BAR; pre-read afA0(0)+bfB0(0) — same ledger as steady state.
// MODE 0: dense + bijective XCD swizzle. MODE 1: causal S, triangular 256-row
// blocks (36/batch). MODE 2: PV, kend = bm0+256, diagonal-shifted map.
// ===========================================================================
#define SGA8(dd, h, i, kt) do{ const int s_ = (h)*16 + (i)*8 + w; \
    gl_lds16(Asb + (size_t)((s_>>1)<<4) * lda + ((s_&1)<<5) + (kt), \
             lds + (dd)*65536 + (s_<<10)); }while(0)
#define SGB8N(dd, g, kt) do{ const int sB_ = (g)*8 + w; \
    const int hi_ = sB_ >> 4, r_ = sB_ & 15; \
    const int wc_ = r_ >> 2, ni_ = hi_*2 + ((r_>>1)&1), kk_ = r_ & 1; \
    gl_lds16(Bsb + (size_t)(wc_*64 + ni_*16) * ldb + (kk_<<5) + (kt), \
             lds + (dd)*65536 + 32768 + (sB_<<10)); }while(0)
#define LDA8(dd, miA, kk) (*(const bf16x8*)(lds + (dd)*65536 + ((sbA + (miA)*2 + (kk)) << 10) + rswz))
#define LDB8N(dd, ni, kk) (*(const bf16x8*)(lds + (dd)*65536 + 32768 + \
    ((((((ni)>>1)<<4) + ((w&3)<<2) + (((ni)&1)<<1) + (kk))) << 10) + rswz))

template<typename CT, int MODE>
__global__ __launch_bounds__(512, 2)
void gemm8p(const __hip_bfloat16* __restrict__ A, const __hip_bfloat16* __restrict__ B,
            CT* __restrict__ C, int K, int lda, int ldb, int ldc, int nbx,
            float alpha, size_t sA, size_t sB, size_t sC)
{
    __shared__ __align__(1024) char lds[131072];

    int bm0, bn0;
    if (MODE == 1) {
        const int wgi = blockIdx.x;
        int by = (int)((sqrtf(8.f * wgi + 1.f) - 1.f) * 0.5f);
        if (by * (by + 1) / 2 > wgi) --by;
        if ((by + 1) * (by + 2) / 2 <= wgi) ++by;
        const int bx = wgi - by * (by + 1) / 2;
        bm0 = by * 256; bn0 = bx * 256;
    } else if (MODE == 2) {
        const int g = blockIdx.x;
        const int nby = gridDim.x / nbx;
        const int bx = g % nbx;
        const int by = (g / nbx + bx) % nby;
        bm0 = by * 256; bn0 = bx * 256;
    } else {
        const int nwg = gridDim.x;
        const int q8 = nwg >> 3, r8 = nwg & 7;
        const int xcd = blockIdx.x & 7, blk = blockIdx.x >> 3;
        const int wg = (xcd < r8 ? xcd * (q8 + 1) : r8 * (q8 + 1) + (xcd - r8) * q8) + blk;
        bm0 = (wg / nbx) * 256; bn0 = (wg % nbx) * 256;
    }

    A += sA * blockIdx.y; B += sB * blockIdx.y; C += sC * blockIdx.y;

    const int tid  = threadIdx.x;
    const int lane = tid & 63;
    const int w    = tid >> 6;

    const int rb   = (lane & 15) * 64 + (lane >> 4) * 16;
    const int rswz = rb ^ (((rb >> 9) & 1) << 5);
    const int sbA  = (w >> 2) * 16;

    const int l16 = lane * 16;
    const int uqs = l16 ^ (((l16 >> 9) & 1) << 5);
    const int rIn = uqs >> 6;
    const int cIn = (uqs & 63) >> 1;
    const __hip_bfloat16* Asb = A + (size_t)(bm0 + rIn) * lda + cIn;
    const __hip_bfloat16* Bsb = B + (size_t)(bn0 + rIn) * ldb + cIn;

    f32x4 acc[8][4] = {};
    bf16x8 afA0[4][2], afA1[4][2], bfB0[2][2], bfB1[2][2];

    const int klim = bm0 + 256;
    const int kend = (MODE == 2) ? (K < klim ? K : klim) : K;
    const int nt   = kend >> 6;         // >= 4 for all our shapes

    // prologue: tile0 {A0,B0,B1,A1} + tile1 {A0,B1,A1}; drain tile0; pre-read
    SGA8(0, 0, 0, 0); SGA8(0, 1, 0, 0);            // A0(0)
    SGB8N(0, 0, 0);   SGB8N(0, 1, 0);              // B0(0)
    SGB8N(0, 2, 0);   SGB8N(0, 3, 0);              // B1(0)
    SGA8(0, 0, 1, 0); SGA8(0, 1, 1, 0);            // A1(0)
    if (nt > 1) {
        SGA8(1, 0, 0, 64); SGA8(1, 1, 0, 64);      // A0(1)
        SGB8N(1, 2, 64);   SGB8N(1, 3, 64);        // B1(1)
        SGA8(1, 0, 1, 64); SGA8(1, 1, 1, 64);      // A1(1)
        WAITV6();
    } else WAITV0();
    BAR();
#pragma unroll
    for (int mi = 0; mi < 4; ++mi) { afA0[mi][0] = LDA8(0, mi, 0); afA0[mi][1] = LDA8(0, mi, 1); }
#pragma unroll
    for (int ni = 0; ni < 2; ++ni) { bfB0[ni][0] = LDB8N(0, ni, 0); bfB0[ni][1] = LDB8N(0, ni, 1); }

    for (int t = 0; t < nt; ++t) {
        const int d   = t & 1, e = d ^ 1;
        const bool p1 = (t + 1) < nt;
        const bool p2 = (t + 2) < nt;
        const int kt1 = (t + 1) << 6;
        const int kt2 = (t + 2) << 6;

        // ---- ph1: q(0,0) = afA0 x bfB0; stage B0(t+1)->e; window-read B1cur
        if (p1) { SGB8N(e, 0, kt1); SGB8N(e, 1, kt1); }
        BAR();
        PRIO1();
#pragma unroll
        for (int mi = 0; mi < 4; ++mi)
#pragma unroll
            for (int ni = 0; ni < 2; ++ni) {
                f32x4 c = acc[mi][ni];
                c = MM(afA0[mi][0], bfB0[ni][0], c);
                c = MM(afA0[mi][1], bfB0[ni][1], c);
                acc[mi][ni] = c;
            }
#pragma unroll
        for (int ni = 0; ni < 2; ++ni) { bfB1[ni][0] = LDB8N(d, 2 + ni, 0); bfB1[ni][1] = LDB8N(d, 2 + ni, 1); }
        PRIO0();
        BAR();

        // ---- ph2: q(0,1) = afA0 x bfB1; stage A0(t+2)->d; vmcnt; read A1cur
        if (p2) { SGA8(d, 0, 0, kt2); SGA8(d, 1, 0, kt2); WAITV8(); }
        else if (p1) WAITV6();
        else WAITV0();
        BAR();
        PRIO1();
#pragma unroll
        for (int mi = 0; mi < 4; ++mi)
#pragma unroll
            for (int ni = 0; ni < 2; ++ni) {
                f32x4 c = acc[mi][2 + ni];
                c = MM(afA0[mi][0], bfB1[ni][0], c);
                c = MM(afA0[mi][1], bfB1[ni][1], c);
                acc[mi][2 + ni] = c;
            }
#pragma unroll
        for (int mi = 0; mi < 4; ++mi) { afA1[mi][0] = LDA8(d, 4 + mi, 0); afA1[mi][1] = LDA8(d, 4 + mi, 1); }
        PRIO0();
        BAR();

        // ---- ph3: q(1,1) = afA1 x bfB1; stage B1(t+2)->d; read A0next (buf e)
        if (p2) { SGB8N(d, 2, kt2); SGB8N(d, 3, kt2); }
        BAR();
        PRIO1();
#pragma unroll
        for (int mi = 0; mi < 4; ++mi)
#pragma unroll
            for (int ni = 0; ni < 2; ++ni) {
                f32x4 c = acc[4 + mi][2 + ni];
                c = MM(afA1[mi][0], bfB1[ni][0], c);
                c = MM(afA1[mi][1], bfB1[ni][1], c);
                acc[4 + mi][2 + ni] = c;
            }
        if (p1) {
#pragma unroll
            for (int mi = 0; mi < 4; ++mi) { afA0[mi][0] = LDA8(e, mi, 0); afA0[mi][1] = LDA8(e, mi, 1); }
        }
        PRIO0();
        BAR();

        // ---- ph4: q(1,0) = afA1 x bfB0; stage A1(t+2)->d; vmcnt; read B0next
        if (p2) { SGA8(d, 0, 1, kt2); SGA8(d, 1, 1, kt2); WAITV6(); }
        else WAITV0();
        BAR();
        PRIO1();
#pragma unroll
        for (int mi = 0; mi < 4; ++mi)
#pragma unroll
            for (int ni = 0; ni < 2; ++ni) {
                f32x4 c = acc[4 + mi][ni];
                c = MM(afA1[mi][0], bfB0[ni][0], c);
                c = MM(afA1[mi][1], bfB0[ni][1], c);
                acc[4 + mi][ni] = c;
            }
        if (p1) {
#pragma unroll
            for (int ni = 0; ni < 2; ++ni) { bfB0[ni][0] = LDB8N(e, ni, 0); bfB0[ni][1] = LDB8N(e, ni, 1); }
        }
        PRIO0();
        BAR();
    }

    // epilogue: C/D layout col=lane&15, row=(lane>>4)*4+j (m89/m91)
    const int cr = (lane >> 4) * 4, cc = lane & 15;
    const int wrow = bm0 + (w >> 2) * 128, wcol = bn0 + (w & 3) * 64;
#pragma unroll
    for (int mi = 0; mi < 8; ++mi)
#pragma unroll
        for (int ni = 0; ni < 4; ++ni) {
            const int row = wrow + mi * 16 + cr;
            const int col = wcol + ni * 16 + cc;
#pragma unroll
            for (int j = 0; j < 4; ++j)
                store_c(C, (size_t)(row + j) * ldc + col, acc[mi][ni][j] * alpha);
        }
}

// ---------------------------------------------------------------------------
__global__ void f32_to_bf16_vec(const float* __restrict__ in,
                                __hip_bfloat16* __restrict__ out, int n4)
{
    int i = blockIdx.x * 256 + threadIdx.x;
    if (i >= n4) return;
    float4 v = ((const float4*)in)[i];
    union { ushort4 u; __hip_bfloat16 h[4]; } o;
    o.h[0] = __float2bfloat16(v.x);
    o.h[1] = __float2bfloat16(v.y);
    o.h[2] = __float2bfloat16(v.z);
    o.h[3] = __float2bfloat16(v.w);
    ((ushort4*)out)[i] = o.u;
}

__global__ void conv_w4(const float* __restrict__ w0, const float* __restrict__ w1,
                        const float* __restrict__ w2, const float* __restrict__ w3,
                        __hip_bfloat16* o0, __hip_bfloat16* o1,
                        __hip_bfloat16* o2, __hip_bfloat16* o3, int n4)
{
    int i = blockIdx.x * 256 + threadIdx.x;
    if (i >= n4) return;
    const float* src; __hip_bfloat16* dst;
    switch (blockIdx.y) {
        case 0: src = w0; dst = o0; break;
        case 1: src = w1; dst = o1; break;
        case 2: src = w2; dst = o2; break;
        default: src = w3; dst = o3; break;
    }
    float4 v = ((const float4*)src)[i];
    union { ushort4 u; __hip_bfloat16 h[4]; } o;
    o.h[0] = __float2bfloat16(v.x);
    o.h[1] = __float2bfloat16(v.y);
    o.h[2] = __float2bfloat16(v.z);
    o.h[3] = __float2bfloat16(v.w);
    ((ushort4*)dst)[i] = o.u;
}

__global__ void rope_table(const int* __restrict__ pos, float2* __restrict__ tab, int N)
{
    int i = blockIdx.x * 256 + threadIdx.x;
    if (i >= N * 64) return;
    int n = i >> 6, j = i & 63;
    float p = (float)pos[n];
    float ang = p * powf(10000.f, -(float)j * (1.0f / 64.0f));
    tab[i] = make_float2(cosf(ang), sinf(ang));
}

__global__ void rope_apply2(__hip_bfloat16* __restrict__ Q, __hip_bfloat16* __restrict__ K,
                            const float2* __restrict__ tab, int ld)
{
    int i = blockIdx.x * 256 + threadIdx.x;
    __hip_bfloat16* T = blockIdx.y ? K : Q;
    int r  = i >> 8;
    int cb = (i & 255) << 3;
    int n  = r & 2047;
    int j0 = (cb >> 1) & 63;
    union { bf16x8 v; __hip_bfloat162 h[4]; } u;
    __hip_bfloat16* p = T + (size_t)r * ld + cb;
    u.v = *(const bf16x8*)p;
#pragma unroll
    for (int k = 0; k < 4; ++k) {
        float2 cs = tab[(n << 6) + j0 + k];
        float x1 = __bfloat162float(u.h[k].x);
        float x2 = __bfloat162float(u.h[k].y);
        u.h[k].x = __float2bfloat16(cs.x * x1 - cs.y * x2);
        u.h[k].y = __float2bfloat16(cs.y * x1 + cs.x * x2);
    }
    *(bf16x8*)p = u.v;
}

// ---------------------------------------------------------------------------
// In-place causal softmax, extent-trimmed (write only to the 256-block
// boundary; PV's kend guarantees cols beyond are never read).
// ---------------------------------------------------------------------------
__global__ void softmax_causal_ip(float* __restrict__ S, int N)
{
    const int q = blockIdx.x;
    float* srow = S + ((size_t)blockIdx.y * N + q) * N;
    __shared__ float buf[2048];
    __shared__ float red[8];
    const int tid = threadIdx.x;
    const int wend = ((q >> 8) + 1) << 8;

    float4* b4 = (float4*)buf;
    const float4* s4 = (const float4*)srow;
    for (int i = tid; i <= (q >> 2); i += 256) b4[i] = s4[i];
    __syncthreads();

    float m = -1e30f;
    for (int j = tid; j <= q; j += 256) m = fmaxf(m, buf[j]);
#pragma unroll
    for (int o = 32; o > 0; o >>= 1) m = fmaxf(m, __shfl_xor(m, o));
    if ((tid & 63) == 0) red[tid >> 6] = m;
    __syncthreads();
    m = fmaxf(fmaxf(red[0], red[1]), fmaxf(red[2], red[3]));

    float sum = 0.f;
    for (int j = tid; j <= q; j += 256) { float e = __expf(buf[j] - m); buf[j] = e; sum += e; }
#pragma unroll
    for (int o = 32; o > 0; o >>= 1) sum += __shfl_xor(sum, o);
    if ((tid & 63) == 0) red[4 + (tid >> 6)] = sum;
    __syncthreads();
    const float inv = 1.f / (red[4] + red[5] + red[6] + red[7]);

    __hip_bfloat162* p2 = (__hip_bfloat162*)srow;
    for (int i = tid; i < (wend >> 1); i += 256) {
        int j0 = i * 2;
        __hip_bfloat162 h;
        h.x = __float2bfloat16(j0     <= q ? buf[j0]     * inv : 0.f);
        h.y = __float2bfloat16(j0 + 1 <= q ? buf[j0 + 1] * inv : 0.f);
        p2[i] = h;
    }
}

// Vt[b][d][k] = V[b][k][d]; V row stride ldv (inside QKV)
__global__ void transpose_bf16(const __hip_bfloat16* __restrict__ V,
                               __hip_bfloat16* __restrict__ Vt, int N, int ldv)
{
    __shared__ __hip_bfloat16 tile[32][33];
    const size_t bi = (size_t)blockIdx.z * N * ldv;
    const size_t bo = (size_t)blockIdx.z * N * N;
    const int k0 = blockIdx.x * 32, d0 = blockIdx.y * 32;
    const int tx = threadIdx.x, ty = threadIdx.y;   // 32 x 8
#pragma unroll
    for (int j = 0; j < 4; ++j)
        tile[ty + 8 * j][tx] = V[bi + (size_t)(k0 + ty + 8 * j) * ldv + d0 + tx];
    __syncthreads();
#pragma unroll
    for (int j = 0; j < 4; ++j)
        Vt[bo + (size_t)(d0 + ty + 8 * j) * N + k0 + tx] = tile[tx][ty + 8 * j];
}

// ---------------------------------------------------------------------------
extern "C" void kernel_launch(void* const* d_in, const int* in_sizes, int n_in,
                              void* d_out, int out_size, void* d_ws, size_t ws_size,
                              hipStream_t stream)
{
    const float* x  = (const float*)d_in[0];
    const int* pos  = (const int*)d_in[1];
    const float* wq = (const float*)d_in[2];
    const float* wk = (const float*)d_in[3];
    const float* wv = (const float*)d_in[4];
    const float* wo = (const float*)d_in[5];
    float* out = (float*)d_out;

    const int B = 4, N = 2048, D = 2048;
    const int M = B * N;                      // 8192
    const int D3 = 3 * D;                     // 6144
    const size_t MB = 1ull << 20;
    if (ws_size < 192 * MB) return;

    char* w = (char*)d_ws;
    __hip_bfloat16* QKV  = (__hip_bfloat16*)(w + 0 * MB);    // 96 MB, ld 6144
    __hip_bfloat16* wqkv = (__hip_bfloat16*)(w + 96 * MB);   // 24 MB
    __hip_bfloat16* wob  = (__hip_bfloat16*)(w + 120 * MB);  //  8 MB
    __hip_bfloat16* xb   = (__hip_bfloat16*)(w + 128 * MB);  // 32 MB, dead after QKV GEMM
    __hip_bfloat16* Vt   = xb;                               // alias
    __hip_bfloat16* AO   = (__hip_bfloat16*)(w + 160 * MB);  // 32 MB
    float2*         tab  = (float2*)(w + 190 * MB);          //  1 MB

    __hip_bfloat16* Qb = QKV;
    __hip_bfloat16* Kb = QKV + D;
    __hip_bfloat16* Vb = QKV + 2 * D;

    float* Sal = (float*)d_out;              // S scratch = d_out (64 MB)

    // 1. converts + RoPE table
    f32_to_bf16_vec<<<(M * D / 4 + 255) / 256, 256, 0, stream>>>(x, xb, M * D / 4);
    conv_w4<<<dim3((D * D / 4 + 255) / 256, 4), 256, 0, stream>>>(
        wq, wk, wv, wo, wqkv, wqkv + (size_t)D * D, wqkv + (size_t)2 * D * D, wob, D * D / 4);
    rope_table<<<(N * 64 + 255) / 256, 256, 0, stream>>>(pos, tab, N);

    // 2. fused QKV projection (768 wgs)
    gemm8p<__hip_bfloat16, 0><<<dim3((D3 / 256) * (M / 256)), 512, 0, stream>>>(
        xb, wqkv, QKV, D, D, D, D3, D3 / 256, 1.f, 0, 0, 0);

    // 3. RoPE on Q and K
    rope_apply2<<<dim3(M, 2), 256, 0, stream>>>(Qb, Kb, tab, D3);

    // 4. V transpose (Vt aliases dead xb)
    transpose_bf16<<<dim3(N / 32, N / 32, B), dim3(32, 8), 0, stream>>>(Vb, Vt, N, D3);

    // 5. attention
    const float scale = 1.0f / sqrtf((float)D);
    const int nbxA = N / 256;                           // 8
    const int ntri = nbxA * (nbxA + 1) / 2;             // 36
    gemm8p<float, 1><<<dim3(ntri, B), 512, 0, stream>>>(
        Qb, Kb, Sal, D, D3, D3, N, nbxA, scale,
        (size_t)N * D3, (size_t)N * D3, (size_t)N * N);
    softmax_causal_ip<<<dim3(N, B), 256, 0, stream>>>(Sal, N);
    gemm8p<__hip_bfloat16, 2><<<dim3(nbxA * nbxA, B), 512, 0, stream>>>(
        (const __hip_bfloat16*)Sal, Vt, AO, N, 2 * N, N, D, nbxA, 1.f,
        (size_t)2 * N * N, (size_t)N * N, (size_t)N * D);

    // 6. output projection
    gemm8p<float, 0><<<dim3((D / 256) * (M / 256)), 512, 0, stream>>>(
        AO, wob, out, D, D, D, D, D / 256, 1.f, 0, 0, 0);
}

// Round 12
// 444.325 us; speedup vs baseline: 1.1471x; 1.0393x over previous
//
#include <hip/hip_runtime.h>
#include <hip/hip_bf16.h>
#include <cstdint>
#include <cmath>

typedef __attribute__((ext_vector_type(4))) float f32x4;
typedef __attribute__((ext_vector_type(8))) short bf16x8;

#define BAR()   __builtin_amdgcn_s_barrier()
#define PRIO1() __builtin_amdgcn_s_setprio(1)
#define PRIO0() __builtin_amdgcn_s_setprio(0)
#define WAITV6() asm volatile("s_waitcnt vmcnt(6)" ::: "memory")
#define WAITV0() asm volatile("s_waitcnt vmcnt(0)" ::: "memory")
#define MM(a,b,c) __builtin_amdgcn_mfma_f32_16x16x32_bf16((a),(b),(c),0,0,0)

__device__ __forceinline__ void gl_lds16(const __hip_bfloat16* g, char* l) {
    __builtin_amdgcn_global_load_lds(
        (const __attribute__((address_space(1))) void*)g,
        (__attribute__((address_space(3))) void*)l, 16, 0, 0);
}
__device__ __forceinline__ void store_c(float* C, size_t i, float v) { C[i] = v; }
__device__ __forceinline__ void store_c(__hip_bfloat16* C, size_t i, float v) { C[i] = __float2bfloat16(v); }

// ===========================================================================
// gemm8p (R10-proven 4-phase schedule, unchanged main loop) + two fusions:
//  - RFUSE: apply interleaved-pair RoPE in the epilogue for cols < 4096
//    (Q,K regions of the fused QKV output). Pair partner is lane^1 (C/D
//    layout: col = wcol+ni*16+(lane&15)), exchanged via __shfl_xor(x,1);
//    cos/sin from tab[(n<<6) + ((col&127)>>1)]. Wave-uniform branch.
//  - MODE 1 (causal S, triangular 256-blocks, nbx = ntri = 36/batch):
//    blocks with blockIdx.x >= nbx instead transpose V (64x64 LDS tiles,
//    [64][66] pad = conflict-free) into Vt — fills the idle CUs of the
//    144-wg S grid; same dependency window (after QKV, before PV).
// MODE 0: dense + bijective XCD swizzle. MODE 2: PV, kend = bm0+256,
// diagonal-shifted map. Schedule: 4 phases/K64-tile, groups = phase
// read-sets, stage {ph1:B0(t+1), ph2:A0(t+2), ph3:B1(t+2), ph4:A1(t+2)},
// vmcnt(6) once per tile at ph4 (R10 ledger).
// ===========================================================================
#define SGA8(dd, h, i, kt) do{ const int s_ = (h)*16 + (i)*8 + w; \
    gl_lds16(Asb + (size_t)((s_>>1)<<4) * lda + ((s_&1)<<5) + (kt), \
             lds + (dd)*65536 + (s_<<10)); }while(0)
#define SGB8N(dd, g, kt) do{ const int sB_ = (g)*8 + w; \
    const int hi_ = sB_ >> 4, r_ = sB_ & 15; \
    const int wc_ = r_ >> 2, ni_ = hi_*2 + ((r_>>1)&1), kk_ = r_ & 1; \
    gl_lds16(Bsb + (size_t)(wc_*64 + ni_*16) * ldb + (kk_<<5) + (kt), \
             lds + (dd)*65536 + 32768 + (sB_<<10)); }while(0)
#define LDA8(dd, miA, kk) (*(const bf16x8*)(lds + (dd)*65536 + ((sbA + (miA)*2 + (kk)) << 10) + rswz))
#define LDB8N(dd, ni, kk) (*(const bf16x8*)(lds + (dd)*65536 + 32768 + \
    ((((((ni)>>1)<<4) + ((w&3)<<2) + (((ni)&1)<<1) + (kk))) << 10) + rswz))

template<typename CT, int MODE, bool RFUSE>
__global__ __launch_bounds__(512, 2)
void gemm8p(const __hip_bfloat16* __restrict__ A, const __hip_bfloat16* __restrict__ B,
            CT* __restrict__ C, int K, int lda, int ldb, int ldc, int nbx,
            float alpha, size_t sA, size_t sB, size_t sC,
            const float2* __restrict__ tab,
            const __hip_bfloat16* __restrict__ Vsrc,
            __hip_bfloat16* __restrict__ Vt, int ldv)
{
    __shared__ __align__(1024) char lds[131072];
    const int tid = threadIdx.x;

    int bm0, bn0;
    if (MODE == 1) {
        if ((int)blockIdx.x >= nbx) {
            // ---- V-transpose worker (fills idle CUs of the S grid) ----
            const int tb  = blockIdx.x - nbx;
            const int ntb = gridDim.x - nbx;
            const __hip_bfloat16* Vg = Vsrc + (size_t)blockIdx.y * 2048 * ldv;
            __hip_bfloat16* Vtg = Vt + (size_t)blockIdx.y * 2048 * 2048;
            __hip_bfloat16 (*tile)[66] = (__hip_bfloat16(*)[66])lds;
            const int tx = tid & 63, ty = tid >> 6;     // 64 x 8
            for (int ti = tb; ti < 1024; ti += ntb) {
                const int k0 = (ti & 31) << 6, d0 = (ti >> 5) << 6;
                __syncthreads();
#pragma unroll
                for (int jj = 0; jj < 8; ++jj)
                    tile[ty + 8 * jj][tx] = Vg[(size_t)(k0 + ty + 8 * jj) * ldv + d0 + tx];
                __syncthreads();
#pragma unroll
                for (int jj = 0; jj < 8; ++jj)
                    Vtg[(size_t)(d0 + ty + 8 * jj) * 2048 + k0 + tx] = tile[tx][ty + 8 * jj];
            }
            return;
        }
        const int wgi = blockIdx.x;
        int by = (int)((sqrtf(8.f * wgi + 1.f) - 1.f) * 0.5f);
        if (by * (by + 1) / 2 > wgi) --by;
        if ((by + 1) * (by + 2) / 2 <= wgi) ++by;
        const int bx = wgi - by * (by + 1) / 2;
        bm0 = by * 256; bn0 = bx * 256;
    } else if (MODE == 2) {
        const int g = blockIdx.x;
        const int nby = gridDim.x / nbx;
        const int bx = g % nbx;
        const int by = (g / nbx + bx) % nby;
        bm0 = by * 256; bn0 = bx * 256;
    } else {
        const int nwg = gridDim.x;
        const int q8 = nwg >> 3, r8 = nwg & 7;
        const int xcd = blockIdx.x & 7, blk = blockIdx.x >> 3;
        const int wg = (xcd < r8 ? xcd * (q8 + 1) : r8 * (q8 + 1) + (xcd - r8) * q8) + blk;
        bm0 = (wg / nbx) * 256; bn0 = (wg % nbx) * 256;
    }

    A += sA * blockIdx.y; B += sB * blockIdx.y; C += sC * blockIdx.y;

    const int lane = tid & 63;
    const int w    = tid >> 6;

    const int rb   = (lane & 15) * 64 + (lane >> 4) * 16;
    const int rswz = rb ^ (((rb >> 9) & 1) << 5);
    const int sbA  = (w >> 2) * 16;

    const int l16 = lane * 16;
    const int uqs = l16 ^ (((l16 >> 9) & 1) << 5);
    const int rIn = uqs >> 6;
    const int cIn = (uqs & 63) >> 1;
    const __hip_bfloat16* Asb = A + (size_t)(bm0 + rIn) * lda + cIn;
    const __hip_bfloat16* Bsb = B + (size_t)(bn0 + rIn) * ldb + cIn;

    f32x4 acc[8][4] = {};
    bf16x8 afA[4][2], bfB[2][2];

    const int klim = bm0 + 256;
    const int kend = (MODE == 2) ? (K < klim ? K : klim) : K;
    const int nt   = kend >> 6;

    // prologue: tile0 {A0,B0,B1,A1} + tile1 {A0,B1,A1}
    SGA8(0, 0, 0, 0); SGA8(0, 1, 0, 0);            // A0(0)
    SGB8N(0, 0, 0);   SGB8N(0, 1, 0);              // B0(0)
    SGB8N(0, 2, 0);   SGB8N(0, 3, 0);              // B1(0)
    SGA8(0, 0, 1, 0); SGA8(0, 1, 1, 0);            // A1(0)
    if (nt > 1) {
        SGA8(1, 0, 0, 64); SGA8(1, 1, 0, 64);      // A0(1)
        SGB8N(1, 2, 64);   SGB8N(1, 3, 64);        // B1(1)
        SGA8(1, 0, 1, 64); SGA8(1, 1, 1, 64);      // A1(1)
        WAITV6();
    } else WAITV0();
    BAR();

    for (int t = 0; t < nt; ++t) {
        const int d   = t & 1, e = d ^ 1;
        const bool p1 = (t + 1) < nt;
        const bool p2 = (t + 2) < nt;
        const int kt1 = (t + 1) << 6;
        const int kt2 = (t + 2) << 6;

        // ---- ph1: (mL,nL) — read A0+B0 frags; stage B0(t+1)->e
#pragma unroll
        for (int mi = 0; mi < 4; ++mi) { afA[mi][0] = LDA8(d, mi, 0); afA[mi][1] = LDA8(d, mi, 1); }
#pragma unroll
        for (int ni = 0; ni < 2; ++ni) { bfB[ni][0] = LDB8N(d, ni, 0); bfB[ni][1] = LDB8N(d, ni, 1); }
        if (p1) { SGB8N(e, 0, kt1); SGB8N(e, 1, kt1); }
        BAR();
        PRIO1();
#pragma unroll
        for (int mi = 0; mi < 4; ++mi)
#pragma unroll
            for (int ni = 0; ni < 2; ++ni) {
                f32x4 c = acc[mi][ni];
                c = MM(afA[mi][0], bfB[ni][0], c);
                c = MM(afA[mi][1], bfB[ni][1], c);
                acc[mi][ni] = c;
            }
        PRIO0();
        BAR();

        // ---- ph2: (mL,nH) — read B1 frags; stage A0(t+2)->d
#pragma unroll
        for (int ni = 0; ni < 2; ++ni) { bfB[ni][0] = LDB8N(d, 2 + ni, 0); bfB[ni][1] = LDB8N(d, 2 + ni, 1); }
        if (p2) { SGA8(d, 0, 0, kt2); SGA8(d, 1, 0, kt2); }
        BAR();
        PRIO1();
#pragma unroll
        for (int mi = 0; mi < 4; ++mi)
#pragma unroll
            for (int ni = 0; ni < 2; ++ni) {
                f32x4 c = acc[mi][2 + ni];
                c = MM(afA[mi][0], bfB[ni][0], c);
                c = MM(afA[mi][1], bfB[ni][1], c);
                acc[mi][2 + ni] = c;
            }
        PRIO0();
        BAR();

        // ---- ph3: (mH,nH) — read A1 frags; stage B1(t+2)->d
#pragma unroll
        for (int mi = 0; mi < 4; ++mi) { afA[mi][0] = LDA8(d, 4 + mi, 0); afA[mi][1] = LDA8(d, 4 + mi, 1); }
        if (p2) { SGB8N(d, 2, kt2); SGB8N(d, 3, kt2); }
        BAR();
        PRIO1();
#pragma unroll
        for (int mi = 0; mi < 4; ++mi)
#pragma unroll
            for (int ni = 0; ni < 2; ++ni) {
                f32x4 c = acc[4 + mi][2 + ni];
                c = MM(afA[mi][0], bfB[ni][0], c);
                c = MM(afA[mi][1], bfB[ni][1], c);
                acc[4 + mi][2 + ni] = c;
            }
        PRIO0();
        BAR();

        // ---- ph4: (mH,nL) — re-read B0 frags; stage A1(t+2)->d; vmcnt(6)
#pragma unroll
        for (int ni = 0; ni < 2; ++ni) { bfB[ni][0] = LDB8N(d, ni, 0); bfB[ni][1] = LDB8N(d, ni, 1); }
        if (p2) { SGA8(d, 0, 1, kt2); SGA8(d, 1, 1, kt2); WAITV6(); }
        else WAITV0();
        BAR();
        PRIO1();
#pragma unroll
        for (int mi = 0; mi < 4; ++mi)
#pragma unroll
            for (int ni = 0; ni < 2; ++ni) {
                f32x4 c = acc[4 + mi][ni];
                c = MM(afA[mi][0], bfB[ni][0], c);
                c = MM(afA[mi][1], bfB[ni][1], c);
                acc[4 + mi][ni] = c;
            }
        PRIO0();
        BAR();
    }

    // epilogue: C/D layout col=lane&15, row=(lane>>4)*4+j (m89/m91)
    const int cr = (lane >> 4) * 4, cc = lane & 15;
    const int wrow = bm0 + (w >> 2) * 128, wcol = bn0 + (w & 3) * 64;
#pragma unroll
    for (int mi = 0; mi < 8; ++mi)
#pragma unroll
        for (int ni = 0; ni < 4; ++ni) {
            const int row = wrow + mi * 16 + cr;
            const int col = wcol + ni * 16 + cc;
            if (RFUSE && col < 4096) {
                // RoPE: pair partner in lane^1 (adjacent col); interleaved pairs
                const int j0 = (col & 127) >> 1;
#pragma unroll
                for (int j = 0; j < 4; ++j) {
                    float xv = acc[mi][ni][j] * alpha;
                    float xp = __shfl_xor(xv, 1);
                    const int n = (row + j) & 2047;
                    float2 cs = tab[(n << 6) + j0];
                    float y = (lane & 1) ? fmaf(cs.y, xp, cs.x * xv)
                                         : fmaf(cs.x, xv, -(cs.y * xp));
                    store_c(C, (size_t)(row + j) * ldc + col, y);
                }
            } else {
#pragma unroll
                for (int j = 0; j < 4; ++j)
                    store_c(C, (size_t)(row + j) * ldc + col, acc[mi][ni][j] * alpha);
            }
        }
}

// ---------------------------------------------------------------------------
// All 5 fp32->bf16 converts in one flat dispatch: x (4M float4) then the
// 4 weights (1M float4 each; wq|wk|wv -> wqkv concat, wo -> wob).
// ---------------------------------------------------------------------------
__global__ void conv5(const float* __restrict__ x,  const float* __restrict__ w0,
                      const float* __restrict__ w1, const float* __restrict__ w2,
                      const float* __restrict__ w3,
                      __hip_bfloat16* __restrict__ xb,
                      __hip_bfloat16* __restrict__ wqkv,
                      __hip_bfloat16* __restrict__ wob)
{
    int i = blockIdx.x * 256 + threadIdx.x;        // over 8M float4
    const float* src; __hip_bfloat16* dst; int off;
    if (i < 4194304) { src = x; dst = xb; off = i; }
    else {
        int k = i - 4194304;
        int ws = k >> 20;
        off = k & 1048575;
        switch (ws) {
            case 0: src = w0; dst = wqkv;                     break;
            case 1: src = w1; dst = wqkv + (size_t)4194304;   break;
            case 2: src = w2; dst = wqkv + (size_t)8388608;   break;
            default: src = w3; dst = wob;                     break;
        }
    }
    float4 v = ((const float4*)src)[off];
    union { ushort4 u; __hip_bfloat16 h[4]; } o;
    o.h[0] = __float2bfloat16(v.x);
    o.h[1] = __float2bfloat16(v.y);
    o.h[2] = __float2bfloat16(v.z);
    o.h[3] = __float2bfloat16(v.w);
    ((ushort4*)dst)[off] = o.u;
}

__global__ void rope_table(const int* __restrict__ pos, float2* __restrict__ tab, int N)
{
    int i = blockIdx.x * 256 + threadIdx.x;
    if (i >= N * 64) return;
    int n = i >> 6, j = i & 63;
    float p = (float)pos[n];
    float ang = p * powf(10000.f, -(float)j * (1.0f / 64.0f));
    tab[i] = make_float2(cosf(ang), sinf(ang));
}

// ---------------------------------------------------------------------------
// In-place causal softmax, extent-trimmed (write only to the 256-block
// boundary; PV's kend guarantees cols beyond are never read).
// ---------------------------------------------------------------------------
__global__ void softmax_causal_ip(float* __restrict__ S, int N)
{
    const int q = blockIdx.x;
    float* srow = S + ((size_t)blockIdx.y * N + q) * N;
    __shared__ float buf[2048];
    __shared__ float red[8];
    const int tid = threadIdx.x;
    const int wend = ((q >> 8) + 1) << 8;

    float4* b4 = (float4*)buf;
    const float4* s4 = (const float4*)srow;
    for (int i = tid; i <= (q >> 2); i += 256) b4[i] = s4[i];
    __syncthreads();

    float m = -1e30f;
    for (int j = tid; j <= q; j += 256) m = fmaxf(m, buf[j]);
#pragma unroll
    for (int o = 32; o > 0; o >>= 1) m = fmaxf(m, __shfl_xor(m, o));
    if ((tid & 63) == 0) red[tid >> 6] = m;
    __syncthreads();
    m = fmaxf(fmaxf(red[0], red[1]), fmaxf(red[2], red[3]));

    float sum = 0.f;
    for (int j = tid; j <= q; j += 256) { float e = __expf(buf[j] - m); buf[j] = e; sum += e; }
#pragma unroll
    for (int o = 32; o > 0; o >>= 1) sum += __shfl_xor(sum, o);
    if ((tid & 63) == 0) red[4 + (tid >> 6)] = sum;
    __syncthreads();
    const float inv = 1.f / (red[4] + red[5] + red[6] + red[7]);

    __hip_bfloat162* p2 = (__hip_bfloat162*)srow;
    for (int i = tid; i < (wend >> 1); i += 256) {
        int j0 = i * 2;
        __hip_bfloat162 h;
        h.x = __float2bfloat16(j0     <= q ? buf[j0]     * inv : 0.f);
        h.y = __float2bfloat16(j0 + 1 <= q ? buf[j0 + 1] * inv : 0.f);
        p2[i] = h;
    }
}

// ---------------------------------------------------------------------------
extern "C" void kernel_launch(void* const* d_in, const int* in_sizes, int n_in,
                              void* d_out, int out_size, void* d_ws, size_t ws_size,
                              hipStream_t stream)
{
    const float* x  = (const float*)d_in[0];
    const int* pos  = (const int*)d_in[1];
    const float* wq = (const float*)d_in[2];
    const float* wk = (const float*)d_in[3];
    const float* wv = (const float*)d_in[4];
    const float* wo = (const float*)d_in[5];
    float* out = (float*)d_out;

    const int B = 4, N = 2048, D = 2048;
    const int M = B * N;                      // 8192
    const int D3 = 3 * D;                     // 6144
    const size_t MB = 1ull << 20;
    if (ws_size < 192 * MB) return;

    char* w = (char*)d_ws;
    __hip_bfloat16* QKV  = (__hip_bfloat16*)(w + 0 * MB);    // 96 MB, ld 6144
    __hip_bfloat16* wqkv = (__hip_bfloat16*)(w + 96 * MB);   // 24 MB
    __hip_bfloat16* wob  = (__hip_bfloat16*)(w + 120 * MB);  //  8 MB
    __hip_bfloat16* xb   = (__hip_bfloat16*)(w + 128 * MB);  // 32 MB, dead after QKV GEMM
    __hip_bfloat16* Vt   = xb;                               // alias
    __hip_bfloat16* AO   = (__hip_bfloat16*)(w + 160 * MB);  // 32 MB
    float2*         tab  = (float2*)(w + 190 * MB);          //  1 MB

    __hip_bfloat16* Qb = QKV;
    __hip_bfloat16* Kb = QKV + D;
    __hip_bfloat16* Vb = QKV + 2 * D;

    float* Sal = (float*)d_out;              // S scratch = d_out (64 MB)

    // 1. converts (one dispatch) + RoPE table
    conv5<<<32768, 256, 0, stream>>>(x, wq, wk, wv, wo, xb, wqkv, wob);
    rope_table<<<(N * 64 + 255) / 256, 256, 0, stream>>>(pos, tab, N);

    // 2. fused QKV projection with in-epilogue RoPE on Q,K (768 wgs)
    gemm8p<__hip_bfloat16, 0, true><<<dim3((D3 / 256) * (M / 256)), 512, 0, stream>>>(
        xb, wqkv, QKV, D, D, D, D3, D3 / 256, 1.f, 0, 0, 0, tab, nullptr, nullptr, 0);

    // 3. attention: S (triangular, 36/batch) + V-transpose on idle blocks
    const float scale = 1.0f / sqrtf((float)D);
    const int nbxA = N / 256;                           // 8
    const int ntri = nbxA * (nbxA + 1) / 2;             // 36
    gemm8p<float, 1, false><<<dim3(64, B), 512, 0, stream>>>(
        Qb, Kb, Sal, D, D3, D3, N, ntri, scale,
        (size_t)N * D3, (size_t)N * D3, (size_t)N * N, nullptr, Vb, Vt, D3);
    softmax_causal_ip<<<dim3(N, B), 256, 0, stream>>>(Sal, N);
    gemm8p<__hip_bfloat16, 2, false><<<dim3(nbxA * nbxA, B), 512, 0, stream>>>(
        (const __hip_bfloat16*)Sal, Vt, AO, N, 2 * N, N, D, nbxA, 1.f,
        (size_t)2 * N * N, (size_t)N * N, (size_t)N * D, nullptr, nullptr, nullptr, 0);

    // 4. output projection
    gemm8p<float, 0, false><<<dim3((D / 256) * (M / 256)), 512, 0, stream>>>(
        AO, wob, out, D, D, D, D, D / 256, 1.f, 0, 0, 0, nullptr, nullptr, nullptr, 0);
}